// Round 1
// baseline (2112.168 us; speedup 1.0000x reference)
//
#include <hip/hip_runtime.h>
#include <hip/hip_bf16.h>

#define N_NODES 20000
#define N_EDGES 150000
#define D 512
#define MPAD 20096   // 157 * 128
#define BN_EPS 1e-5f

typedef __attribute__((ext_vector_type(8))) short s16x8;
typedef __attribute__((ext_vector_type(4))) float f32x4;

__device__ __forceinline__ short f2bf(float f) {
    union { float f; unsigned u; } v; v.f = f;
    unsigned r = (v.u + 0x7fff + ((v.u >> 16) & 1)) >> 16;
    return (short)r;
}

// ---------------- W -> bf16 ----------------
__global__ __launch_bounds__(256) void convert_W(const float* __restrict__ W, short* __restrict__ Wb) {
    int idx = (blockIdx.x * 256 + threadIdx.x) * 8;   // 512*512 / 8 = 32768 threads
    float4 a = *(const float4*)(W + idx);
    float4 b = *(const float4*)(W + idx + 4);
    s16x8 o;
    o[0] = f2bf(a.x); o[1] = f2bf(a.y); o[2] = f2bf(a.z); o[3] = f2bf(a.w);
    o[4] = f2bf(b.x); o[5] = f2bf(b.y); o[6] = f2bf(b.z); o[7] = f2bf(b.w);
    *(s16x8*)(Wb + idx) = o;
}

// ---------------- edge scatter: agg[dst] += x[src], indeg[dst]++ ----------------
__global__ __launch_bounds__(256) void scatter(const float* __restrict__ x,
                                               const int* __restrict__ src,
                                               const int* __restrict__ dst,
                                               float* __restrict__ agg,
                                               int* __restrict__ indeg) {
    int gwave = (blockIdx.x * 256 + threadIdx.x) >> 6;
    int lane = threadIdx.x & 63;
    if (gwave >= N_EDGES) return;
    int s = src[gwave];
    int d = dst[gwave];
    const float4* xs = (const float4*)(x + (size_t)s * D);
    float* ad = agg + (size_t)d * D;
    float4 v0 = xs[lane * 2];
    float4 v1 = xs[lane * 2 + 1];
    int o = lane * 8;
    atomicAdd(ad + o + 0, v0.x); atomicAdd(ad + o + 1, v0.y);
    atomicAdd(ad + o + 2, v0.z); atomicAdd(ad + o + 3, v0.w);
    atomicAdd(ad + o + 4, v1.x); atomicAdd(ad + o + 5, v1.y);
    atomicAdd(ad + o + 6, v1.z); atomicAdd(ad + o + 7, v1.w);
    if (lane == 0) atomicAdd(indeg + d, 1);
}

// ---------------- select (indeg>0 ? agg : x) -> bf16, pad rows = 0 ----------------
__global__ __launch_bounds__(256) void select_convert(const float* __restrict__ x,
                                                      const float* __restrict__ agg,
                                                      const int* __restrict__ indeg,
                                                      short* __restrict__ Ab) {
    size_t idx = ((size_t)blockIdx.x * 256 + threadIdx.x) * 8;  // over MPAD*512
    int m = (int)(idx >> 9);
    s16x8 o;
    if (m >= N_NODES) {
        o = (s16x8)0;
    } else {
        const float* p = (indeg[m] > 0) ? (agg + idx) : (x + idx);
        float4 a = *(const float4*)p;
        float4 b = *(const float4*)(p + 4);
        o[0] = f2bf(a.x); o[1] = f2bf(a.y); o[2] = f2bf(a.z); o[3] = f2bf(a.w);
        o[4] = f2bf(b.x); o[5] = f2bf(b.y); o[6] = f2bf(b.z); o[7] = f2bf(b.w);
    }
    *(s16x8*)(Ab + idx) = o;
}

// ---------------- GEMM: out = relu(A @ W^T + bias), A bf16 [MPAD][512], Wb [512][512] ----------------
#define BM 128
#define BNT 128
#define BK 32

__global__ __launch_bounds__(256) void gemm_relu(const short* __restrict__ A,
                                                 const short* __restrict__ B,
                                                 const float* __restrict__ bias,
                                                 float* __restrict__ out) {
    __shared__ short As[BM * BK];
    __shared__ short Bs[BNT * BK];
    int tid = threadIdx.x;
    int lane = tid & 63;
    int wave = tid >> 6;
    int wr = wave >> 1, wc = wave & 1;   // 2x2 waves, each 64x64
    int m0 = blockIdx.x * BM;
    int n0 = blockIdx.y * BNT;

    f32x4 acc[4][4] = {};

    for (int kt = 0; kt < D; kt += BK) {
        s16x8 ra[2], rb[2];
        #pragma unroll
        for (int it = 0; it < 2; ++it) {
            int c = tid + it * 256;          // chunk 0..511 (8 bf16 each)
            int row = c >> 2;
            int kc = (c & 3) * 8;
            ra[it] = *(const s16x8*)(A + (size_t)(m0 + row) * D + kt + kc);
            rb[it] = *(const s16x8*)(B + (size_t)(n0 + row) * D + kt + kc);
        }
        __syncthreads();
        #pragma unroll
        for (int it = 0; it < 2; ++it) {
            int c = tid + it * 256;
            *(s16x8*)(As + c * 8) = ra[it];
            *(s16x8*)(Bs + c * 8) = rb[it];
        }
        __syncthreads();
        s16x8 af[4], bf[4];
        int ko = (lane >> 4) * 8;
        #pragma unroll
        for (int m = 0; m < 4; ++m)
            af[m] = *(const s16x8*)(As + (wr * 64 + m * 16 + (lane & 15)) * BK + ko);
        #pragma unroll
        for (int n = 0; n < 4; ++n)
            bf[n] = *(const s16x8*)(Bs + (wc * 64 + n * 16 + (lane & 15)) * BK + ko);
        #pragma unroll
        for (int m = 0; m < 4; ++m)
            #pragma unroll
            for (int n = 0; n < 4; ++n)
                acc[m][n] = __builtin_amdgcn_mfma_f32_16x16x32_bf16(af[m], bf[n], acc[m][n], 0, 0, 0);
    }

    #pragma unroll
    for (int n = 0; n < 4; ++n) {
        int col = n0 + wc * 64 + n * 16 + (lane & 15);
        float bv = bias[col];
        #pragma unroll
        for (int m = 0; m < 4; ++m) {
            int rbase = m0 + wr * 64 + m * 16 + (lane >> 4) * 4;
            #pragma unroll
            for (int r = 0; r < 4; ++r) {
                int row = rbase + r;
                if (row < N_NODES) {
                    float v = acc[m][n][r] + bv;
                    out[(size_t)row * D + col] = v > 0.f ? v : 0.f;
                }
            }
        }
    }
}

// ---------------- column stats ----------------
__global__ __launch_bounds__(256) void colstats(const float* __restrict__ out,
                                                float* __restrict__ colsum,
                                                float* __restrict__ colsumsq) {
    int col = blockIdx.x * 256 + threadIdx.x;   // grid.x = 2
    int r0 = blockIdx.y * 250;                  // grid.y = 80
    float s = 0.f, q = 0.f;
    for (int r = 0; r < 250; ++r) {
        float v = out[(size_t)(r0 + r) * D + col];
        s += v;
        q += v * v;
    }
    atomicAdd(&colsum[col], s);
    atomicAdd(&colsumsq[col], q);
}

__global__ void bn_prep(const float* __restrict__ colsum, const float* __restrict__ colsumsq,
                        const float* __restrict__ gamma, const float* __restrict__ beta,
                        float* __restrict__ scale, float* __restrict__ shift) {
    int c = threadIdx.x;  // 512 threads
    float mean = colsum[c] * (1.f / N_NODES);
    float var = colsumsq[c] * (1.f / N_NODES) - mean * mean;
    float rs = rsqrtf(var + BN_EPS);
    float sc = gamma[c] * rs;
    scale[c] = sc;
    shift[c] = beta[c] - mean * sc;
}

__global__ __launch_bounds__(256) void bn_apply(float* __restrict__ out,
                                                const float* __restrict__ scale,
                                                const float* __restrict__ shift) {
    const int total = N_NODES * D / 4;
    for (int i = blockIdx.x * 256 + threadIdx.x; i < total; i += gridDim.x * 256) {
        float4 v = ((float4*)out)[i];
        int c0 = (i * 4) & (D - 1);
        float4 sc = *(const float4*)(scale + c0);
        float4 sh = *(const float4*)(shift + c0);
        v.x = v.x * sc.x + sh.x;
        v.y = v.y * sc.y + sh.y;
        v.z = v.z * sc.z + sh.z;
        v.w = v.w * sc.w + sh.w;
        ((float4*)out)[i] = v;
    }
}

extern "C" void kernel_launch(void* const* d_in, const int* in_sizes, int n_in,
                              void* d_out, int out_size, void* d_ws, size_t ws_size,
                              hipStream_t stream) {
    const float* x     = (const float*)d_in[0];
    const int*   src   = (const int*)d_in[1];
    const int*   dst   = (const int*)d_in[2];
    const float* W     = (const float*)d_in[3];
    const float* bias  = (const float*)d_in[4];
    const float* gamma = (const float*)d_in[5];
    const float* beta  = (const float*)d_in[6];
    float* out = (float*)d_out;

    char* ws = (char*)d_ws;
    size_t off = 0;
    float* agg      = (float*)(ws + off); off += (size_t)MPAD * D * 4;
    int*   indeg    = (int*)(ws + off);   off += (size_t)MPAD * 4;
    float* colsum   = (float*)(ws + off); off += D * 4;
    float* colsumsq = (float*)(ws + off); off += D * 4;
    size_t zero_bytes = off;                 // everything above zeroed each call
    float* scale    = (float*)(ws + off); off += D * 4;
    float* shift    = (float*)(ws + off); off += D * 4;
    short* Wb       = (short*)(ws + off); off += (size_t)D * D * 2;
    short* Ab       = (short*)(ws + off); off += (size_t)MPAD * D * 2;

    hipMemsetAsync(d_ws, 0, zero_bytes, stream);

    convert_W<<<dim3(128), dim3(256), 0, stream>>>(W, Wb);
    scatter<<<dim3((N_EDGES + 3) / 4), dim3(256), 0, stream>>>(x, src, dst, agg, indeg);
    select_convert<<<dim3((MPAD * D) / (256 * 8)), dim3(256), 0, stream>>>(x, agg, indeg, Ab);
    gemm_relu<<<dim3(MPAD / BM, D / BNT), dim3(256), 0, stream>>>(Ab, Wb, bias, out);
    colstats<<<dim3(2, 80), dim3(256), 0, stream>>>(out, colsum, colsumsq);
    bn_prep<<<dim3(1), dim3(512), 0, stream>>>(colsum, colsumsq, gamma, beta, scale, shift);
    bn_apply<<<dim3(2560), dim3(256), 0, stream>>>(out, scale, shift);
}

// Round 2
// 177.191 us; speedup vs baseline: 11.9203x; 11.9203x over previous
//
#include <hip/hip_runtime.h>
#include <hip/hip_bf16.h>

#define N_NODES 20000
#define N_EDGES 150000
#define D 512
#define MPAD 20096   // 157 * 128
#define BN_EPS 1e-5f

typedef __attribute__((ext_vector_type(8))) short s16x8;
typedef __attribute__((ext_vector_type(4))) float f32x4;

__device__ __forceinline__ short f2bf(float f) {
    union { float f; unsigned u; } v; v.f = f;
    unsigned r = (v.u + 0x7fff + ((v.u >> 16) & 1)) >> 16;
    return (short)r;
}

// ---------------- W -> bf16 ----------------
__global__ __launch_bounds__(256) void convert_W(const float* __restrict__ W, short* __restrict__ Wb) {
    int idx = (blockIdx.x * 256 + threadIdx.x) * 8;
    float4 a = *(const float4*)(W + idx);
    float4 b = *(const float4*)(W + idx + 4);
    s16x8 o;
    o[0] = f2bf(a.x); o[1] = f2bf(a.y); o[2] = f2bf(a.z); o[3] = f2bf(a.w);
    o[4] = f2bf(b.x); o[5] = f2bf(b.y); o[6] = f2bf(b.z); o[7] = f2bf(b.w);
    *(s16x8*)(Wb + idx) = o;
}

// ---------------- CSR build ----------------
__global__ __launch_bounds__(256) void count_edges(const int* __restrict__ dst, int* __restrict__ count) {
    int i = blockIdx.x * 256 + threadIdx.x;
    if (i < N_EDGES) atomicAdd(&count[dst[i]], 1);
}

#define SCAN_T 1024
__global__ __launch_bounds__(SCAN_T) void scan_csr(const int* __restrict__ count,
                                                   int* __restrict__ rowstart,
                                                   int* __restrict__ cursor) {
    __shared__ int partial[SCAN_T];
    int t = threadIdx.x;
    const int CH = (N_NODES + SCAN_T - 1) / SCAN_T;  // 20
    int base = t * CH;
    int s = 0;
    for (int j = 0; j < CH; ++j) {
        int idx = base + j;
        if (idx < N_NODES) s += count[idx];
    }
    partial[t] = s;
    __syncthreads();
    // Hillis-Steele inclusive scan
    for (int off = 1; off < SCAN_T; off <<= 1) {
        int v = (t >= off) ? partial[t - off] : 0;
        __syncthreads();
        partial[t] += v;
        __syncthreads();
    }
    int run = (t == 0) ? 0 : partial[t - 1];
    for (int j = 0; j < CH; ++j) {
        int idx = base + j;
        if (idx < N_NODES) {
            rowstart[idx] = run;
            cursor[idx] = run;
            run += count[idx];
        }
    }
    if (t == SCAN_T - 1) rowstart[N_NODES] = partial[SCAN_T - 1];
}

__global__ __launch_bounds__(256) void fill_edges(const int* __restrict__ src,
                                                  const int* __restrict__ dst,
                                                  int* __restrict__ cursor,
                                                  int* __restrict__ esrc) {
    int i = blockIdx.x * 256 + threadIdx.x;
    if (i < N_EDGES) {
        int p = atomicAdd(&cursor[dst[i]], 1);
        esrc[p] = src[i];
    }
}

// ---------------- gather + indeg-select + bf16 convert ----------------
// one wave per node; lane owns 8 columns
__global__ __launch_bounds__(256) void gather_convert(const float* __restrict__ x,
                                                      const int* __restrict__ rowstart,
                                                      const int* __restrict__ esrc,
                                                      short* __restrict__ Ab) {
    int node = (blockIdx.x * 256 + threadIdx.x) >> 6;
    int lane = threadIdx.x & 63;
    if (node >= MPAD) return;
    size_t colbase = (size_t)lane * 8;
    s16x8 o;
    if (node >= N_NODES) {
        o = (s16x8)0;
    } else {
        int e0 = rowstart[node], e1 = rowstart[node + 1];
        float4 a0, a1;
        if (e0 == e1) {
            const float4* p = (const float4*)(x + (size_t)node * D + colbase);
            a0 = p[0]; a1 = p[1];
        } else {
            a0 = make_float4(0.f, 0.f, 0.f, 0.f);
            a1 = a0;
            for (int e = e0; e < e1; ++e) {
                int s = esrc[e];
                const float4* p = (const float4*)(x + (size_t)s * D + colbase);
                float4 v0 = p[0], v1 = p[1];
                a0.x += v0.x; a0.y += v0.y; a0.z += v0.z; a0.w += v0.w;
                a1.x += v1.x; a1.y += v1.y; a1.z += v1.z; a1.w += v1.w;
            }
        }
        o[0] = f2bf(a0.x); o[1] = f2bf(a0.y); o[2] = f2bf(a0.z); o[3] = f2bf(a0.w);
        o[4] = f2bf(a1.x); o[5] = f2bf(a1.y); o[6] = f2bf(a1.z); o[7] = f2bf(a1.w);
    }
    *(s16x8*)(Ab + (size_t)node * D + colbase) = o;
}

// ---------------- GEMM: out = relu(A @ W^T + bias) ----------------
#define BM 128
#define BNT 128
#define BK 32

__global__ __launch_bounds__(256) void gemm_relu(const short* __restrict__ A,
                                                 const short* __restrict__ B,
                                                 const float* __restrict__ bias,
                                                 float* __restrict__ out) {
    __shared__ short As[BM * BK];
    __shared__ short Bs[BNT * BK];
    int tid = threadIdx.x;
    int lane = tid & 63;
    int wave = tid >> 6;
    int wr = wave >> 1, wc = wave & 1;
    int m0 = blockIdx.x * BM;
    int n0 = blockIdx.y * BNT;

    f32x4 acc[4][4] = {};

    for (int kt = 0; kt < D; kt += BK) {
        s16x8 ra[2], rb[2];
        #pragma unroll
        for (int it = 0; it < 2; ++it) {
            int c = tid + it * 256;
            int row = c >> 2;
            int kc = (c & 3) * 8;
            ra[it] = *(const s16x8*)(A + (size_t)(m0 + row) * D + kt + kc);
            rb[it] = *(const s16x8*)(B + (size_t)(n0 + row) * D + kt + kc);
        }
        __syncthreads();
        #pragma unroll
        for (int it = 0; it < 2; ++it) {
            int c = tid + it * 256;
            *(s16x8*)(As + c * 8) = ra[it];
            *(s16x8*)(Bs + c * 8) = rb[it];
        }
        __syncthreads();
        s16x8 af[4], bf[4];
        int ko = (lane >> 4) * 8;
        #pragma unroll
        for (int m = 0; m < 4; ++m)
            af[m] = *(const s16x8*)(As + (wr * 64 + m * 16 + (lane & 15)) * BK + ko);
        #pragma unroll
        for (int n = 0; n < 4; ++n)
            bf[n] = *(const s16x8*)(Bs + (wc * 64 + n * 16 + (lane & 15)) * BK + ko);
        #pragma unroll
        for (int m = 0; m < 4; ++m)
            #pragma unroll
            for (int n = 0; n < 4; ++n)
                acc[m][n] = __builtin_amdgcn_mfma_f32_16x16x32_bf16(af[m], bf[n], acc[m][n], 0, 0, 0);
    }

    #pragma unroll
    for (int n = 0; n < 4; ++n) {
        int col = n0 + wc * 64 + n * 16 + (lane & 15);
        float bv = bias[col];
        #pragma unroll
        for (int m = 0; m < 4; ++m) {
            int rbase = m0 + wr * 64 + m * 16 + (lane >> 4) * 4;
            #pragma unroll
            for (int r = 0; r < 4; ++r) {
                int row = rbase + r;
                if (row < N_NODES) {
                    float v = acc[m][n][r] + bv;
                    out[(size_t)row * D + col] = v > 0.f ? v : 0.f;
                }
            }
        }
    }
}

// ---------------- column stats + BN ----------------
__global__ __launch_bounds__(256) void colstats(const float* __restrict__ out,
                                                float* __restrict__ colsum,
                                                float* __restrict__ colsumsq) {
    int col = blockIdx.x * 256 + threadIdx.x;
    int r0 = blockIdx.y * 250;
    float s = 0.f, q = 0.f;
    for (int r = 0; r < 250; ++r) {
        float v = out[(size_t)(r0 + r) * D + col];
        s += v;
        q += v * v;
    }
    atomicAdd(&colsum[col], s);
    atomicAdd(&colsumsq[col], q);
}

__global__ void bn_prep(const float* __restrict__ colsum, const float* __restrict__ colsumsq,
                        const float* __restrict__ gamma, const float* __restrict__ beta,
                        float* __restrict__ scale, float* __restrict__ shift) {
    int c = threadIdx.x;
    float mean = colsum[c] * (1.f / N_NODES);
    float var = colsumsq[c] * (1.f / N_NODES) - mean * mean;
    float rs = rsqrtf(var + BN_EPS);
    float sc = gamma[c] * rs;
    scale[c] = sc;
    shift[c] = beta[c] - mean * sc;
}

__global__ __launch_bounds__(256) void bn_apply(float* __restrict__ out,
                                                const float* __restrict__ scale,
                                                const float* __restrict__ shift) {
    const int total = N_NODES * D / 4;
    for (int i = blockIdx.x * 256 + threadIdx.x; i < total; i += gridDim.x * 256) {
        float4 v = ((float4*)out)[i];
        int c0 = (i * 4) & (D - 1);
        float4 sc = *(const float4*)(scale + c0);
        float4 sh = *(const float4*)(shift + c0);
        v.x = v.x * sc.x + sh.x;
        v.y = v.y * sc.y + sh.y;
        v.z = v.z * sc.z + sh.z;
        v.w = v.w * sc.w + sh.w;
        ((float4*)out)[i] = v;
    }
}

extern "C" void kernel_launch(void* const* d_in, const int* in_sizes, int n_in,
                              void* d_out, int out_size, void* d_ws, size_t ws_size,
                              hipStream_t stream) {
    const float* x     = (const float*)d_in[0];
    const int*   src   = (const int*)d_in[1];
    const int*   dst   = (const int*)d_in[2];
    const float* W     = (const float*)d_in[3];
    const float* bias  = (const float*)d_in[4];
    const float* gamma = (const float*)d_in[5];
    const float* beta  = (const float*)d_in[6];
    float* out = (float*)d_out;

    char* ws = (char*)d_ws;
    size_t off = 0;
    int*   count    = (int*)(ws + off);   off += (size_t)N_NODES * 4;
    float* colsum   = (float*)(ws + off); off += D * 4;
    float* colsumsq = (float*)(ws + off); off += D * 4;
    size_t zero_bytes = off;                 // zeroed each call (~84 KB)
    int*   rowstart = (int*)(ws + off);   off += (size_t)(N_NODES + 1) * 4;
    int*   cursor   = (int*)(ws + off);   off += (size_t)N_NODES * 4;
    int*   esrc     = (int*)(ws + off);   off += (size_t)N_EDGES * 4;
    float* scale    = (float*)(ws + off); off += D * 4;
    float* shift    = (float*)(ws + off); off += D * 4;
    short* Wb       = (short*)(ws + off); off += (size_t)D * D * 2;
    short* Ab       = (short*)(ws + off); off += (size_t)MPAD * D * 2;

    hipMemsetAsync(d_ws, 0, zero_bytes, stream);

    convert_W<<<dim3(128), dim3(256), 0, stream>>>(W, Wb);
    count_edges<<<dim3((N_EDGES + 255) / 256), dim3(256), 0, stream>>>(dst, count);
    scan_csr<<<dim3(1), dim3(SCAN_T), 0, stream>>>(count, rowstart, cursor);
    fill_edges<<<dim3((N_EDGES + 255) / 256), dim3(256), 0, stream>>>(src, dst, cursor, esrc);
    gather_convert<<<dim3(MPAD / 4), dim3(256), 0, stream>>>(x, rowstart, esrc, Ab);
    gemm_relu<<<dim3(MPAD / BM, D / BNT), dim3(256), 0, stream>>>(Ab, Wb, bias, out);
    colstats<<<dim3(2, 80), dim3(256), 0, stream>>>(out, colsum, colsumsq);
    bn_prep<<<dim3(1), dim3(512), 0, stream>>>(colsum, colsumsq, gamma, beta, scale, shift);
    bn_apply<<<dim3(2560), dim3(256), 0, stream>>>(out, scale, shift);
}

// Round 3
// 146.367 us; speedup vs baseline: 14.4306x; 1.2106x over previous
//
#include <hip/hip_runtime.h>
#include <hip/hip_bf16.h>

#define N_NODES 20000
#define N_EDGES 150000
#define D 512
#define MPAD 20096   // 157 * 128
#define BN_EPS 1e-5f

typedef __attribute__((ext_vector_type(8))) short s16x8;
typedef __attribute__((ext_vector_type(4))) float f32x4;

__device__ __forceinline__ short f2bf(float f) {
    union { float f; unsigned u; } v; v.f = f;
    unsigned r = (v.u + 0x7fff + ((v.u >> 16) & 1)) >> 16;
    return (short)r;
}
__device__ __forceinline__ float bf2f(short b) {
    union { unsigned u; float f; } c;
    c.u = ((unsigned)(unsigned short)b) << 16;
    return c.f;
}
__device__ __forceinline__ s16x8 cvt8(const float* p) {
    float4 a = *(const float4*)p;
    float4 b = *(const float4*)(p + 4);
    s16x8 o;
    o[0] = f2bf(a.x); o[1] = f2bf(a.y); o[2] = f2bf(a.z); o[3] = f2bf(a.w);
    o[4] = f2bf(b.x); o[5] = f2bf(b.y); o[6] = f2bf(b.z); o[7] = f2bf(b.w);
    return o;
}

__device__ __forceinline__ void load_lds16(const short* g, short* l) {
    __builtin_amdgcn_global_load_lds((const __attribute__((address_space(1))) void*)g,
                                     (__attribute__((address_space(3))) void*)l, 16, 0, 0);
}

// ---------------- prep: W->bf16, x->bf16, count in-degrees ----------------
#define WCH (D * D / 8)            // 32768 chunks
#define XCH (N_NODES * D / 8)      // 1,280,000 chunks
__global__ __launch_bounds__(256) void prep(const float* __restrict__ W,
                                            const float* __restrict__ x,
                                            const int* __restrict__ dst,
                                            short* __restrict__ Wb,
                                            short* __restrict__ Xb,
                                            int* __restrict__ count) {
    int t = blockIdx.x * 256 + threadIdx.x;
    if (t < WCH) {
        *(s16x8*)(Wb + (size_t)t * 8) = cvt8(W + (size_t)t * 8);
    } else if (t < WCH + XCH) {
        size_t idx = (size_t)(t - WCH) * 8;
        *(s16x8*)(Xb + idx) = cvt8(x + idx);
    }
    if (t < N_EDGES / 8) {
        #pragma unroll
        for (int j = 0; j < 8; ++j) atomicAdd(&count[dst[t * 8 + j]], 1);
    }
}

// ---------------- CSR scan + fill ----------------
#define SCAN_T 1024
__global__ __launch_bounds__(SCAN_T) void scan_csr(const int* __restrict__ count,
                                                   int* __restrict__ rowstart,
                                                   int* __restrict__ cursor) {
    __shared__ int partial[SCAN_T];
    int t = threadIdx.x;
    const int CH = (N_NODES + SCAN_T - 1) / SCAN_T;  // 20
    int base = t * CH;
    int s = 0;
    for (int j = 0; j < CH; ++j) {
        int idx = base + j;
        if (idx < N_NODES) s += count[idx];
    }
    partial[t] = s;
    __syncthreads();
    for (int off = 1; off < SCAN_T; off <<= 1) {
        int v = (t >= off) ? partial[t - off] : 0;
        __syncthreads();
        partial[t] += v;
        __syncthreads();
    }
    int run = (t == 0) ? 0 : partial[t - 1];
    for (int j = 0; j < CH; ++j) {
        int idx = base + j;
        if (idx < N_NODES) {
            rowstart[idx] = run;
            cursor[idx] = run;
            run += count[idx];
        }
    }
    if (t == SCAN_T - 1) rowstart[N_NODES] = partial[SCAN_T - 1];
}

__global__ __launch_bounds__(256) void fill_edges(const int* __restrict__ src,
                                                  const int* __restrict__ dst,
                                                  int* __restrict__ cursor,
                                                  int* __restrict__ esrc) {
    int i = blockIdx.x * 256 + threadIdx.x;
    if (i < N_EDGES) {
        int p = atomicAdd(&cursor[dst[i]], 1);
        esrc[p] = src[i];
    }
}

// ---------------- gather (bf16 in, f32 accum, bf16 out) ----------------
__global__ __launch_bounds__(256) void gather_bf16(const short* __restrict__ Xb,
                                                   const int* __restrict__ rowstart,
                                                   const int* __restrict__ esrc,
                                                   short* __restrict__ Ab) {
    int node = (blockIdx.x * 256 + threadIdx.x) >> 6;
    int lane = threadIdx.x & 63;
    if (node >= MPAD) return;
    size_t cb = (size_t)lane * 8;
    s16x8 o;
    if (node >= N_NODES) {
        o = (s16x8)0;
    } else {
        int e0 = rowstart[node], e1 = rowstart[node + 1];
        if (e0 == e1) {
            o = *(const s16x8*)(Xb + (size_t)node * D + cb);
        } else {
            float a[8] = {};
            for (int e = e0; e < e1; ++e) {
                int s = esrc[e];
                s16x8 v = *(const s16x8*)(Xb + (size_t)s * D + cb);
                #pragma unroll
                for (int i = 0; i < 8; ++i) a[i] += bf2f(v[i]);
            }
            #pragma unroll
            for (int i = 0; i < 8; ++i) o[i] = f2bf(a[i]);
        }
    }
    *(s16x8*)(Ab + (size_t)node * D + cb) = o;
}

// ---------------- GEMM: out = relu(A @ W^T + bias), fused column stats ----------------
#define BM 128
#define BNT 128
#define BK 32

__global__ __launch_bounds__(256) void gemm_relu_stats(const short* __restrict__ A,
                                                       const short* __restrict__ B,
                                                       const float* __restrict__ bias,
                                                       float* __restrict__ out,
                                                       float* __restrict__ colsum,
                                                       float* __restrict__ colsumsq) {
    __shared__ short As[BM * BK];   // 8 KB, linear [row][k]
    __shared__ short Bs[BNT * BK];  // 8 KB
    int tid = threadIdx.x;
    int lane = tid & 63;
    int wave = tid >> 6;
    int wr = wave >> 1, wc = wave & 1;
    int m0 = blockIdx.x * BM;
    int n0 = blockIdx.y * BNT;

    f32x4 acc[4][4] = {};

    // staging addresses: wave handles chunks {2*wave, 2*wave+1}; chunk c = rows c*16..c*16+15
    int srow = lane >> 2;            // 0..15
    int scol = (lane & 3) * 8;       // shorts
    const short* Ag = A + (size_t)(m0 + wave * 32 + srow) * D + scol;
    const short* Bg = B + (size_t)(n0 + wave * 32 + srow) * D + scol;
    short* Asl = As + wave * 1024;   // chunk base (shorts): 2*wave * 512
    short* Bsl = Bs + wave * 1024;

    for (int kt = 0; kt < D; kt += BK) {
        #pragma unroll
        for (int j = 0; j < 2; ++j) {
            load_lds16(Ag + (size_t)j * 16 * D + kt, Asl + j * 512);
            load_lds16(Bg + (size_t)j * 16 * D + kt, Bsl + j * 512);
        }
        __syncthreads();
        s16x8 af[4], bfr[4];
        int ko = (lane >> 4) * 8;
        #pragma unroll
        for (int m = 0; m < 4; ++m)
            af[m] = *(const s16x8*)(As + (wr * 64 + m * 16 + (lane & 15)) * BK + ko);
        #pragma unroll
        for (int n = 0; n < 4; ++n)
            bfr[n] = *(const s16x8*)(Bs + (wc * 64 + n * 16 + (lane & 15)) * BK + ko);
        #pragma unroll
        for (int m = 0; m < 4; ++m)
            #pragma unroll
            for (int n = 0; n < 4; ++n)
                acc[m][n] = __builtin_amdgcn_mfma_f32_16x16x32_bf16(af[m], bfr[n], acc[m][n], 0, 0, 0);
        __syncthreads();
    }

    #pragma unroll
    for (int n = 0; n < 4; ++n) {
        int col = n0 + wc * 64 + n * 16 + (lane & 15);
        float bv = bias[col];
        float s = 0.f, q = 0.f;
        #pragma unroll
        for (int m = 0; m < 4; ++m) {
            int rbase = m0 + wr * 64 + m * 16 + (lane >> 4) * 4;
            #pragma unroll
            for (int r = 0; r < 4; ++r) {
                int row = rbase + r;
                if (row < N_NODES) {
                    float v = acc[m][n][r] + bv;
                    v = v > 0.f ? v : 0.f;
                    out[(size_t)row * D + col] = v;
                    s += v;
                    q += v * v;
                }
            }
        }
        s += __shfl_xor(s, 16, 64);
        s += __shfl_xor(s, 32, 64);
        q += __shfl_xor(q, 16, 64);
        q += __shfl_xor(q, 32, 64);
        if (lane < 16) {
            atomicAdd(&colsum[col], s);
            atomicAdd(&colsumsq[col], q);
        }
    }
}

// ---------------- BN ----------------
__global__ void bn_prep(const float* __restrict__ colsum, const float* __restrict__ colsumsq,
                        const float* __restrict__ gamma, const float* __restrict__ beta,
                        float* __restrict__ scale, float* __restrict__ shift) {
    int c = threadIdx.x;
    float mean = colsum[c] * (1.f / N_NODES);
    float var = colsumsq[c] * (1.f / N_NODES) - mean * mean;
    float rs = rsqrtf(var + BN_EPS);
    float sc = gamma[c] * rs;
    scale[c] = sc;
    shift[c] = beta[c] - mean * sc;
}

__global__ __launch_bounds__(256) void bn_apply(float* __restrict__ out,
                                                const float* __restrict__ scale,
                                                const float* __restrict__ shift) {
    const int total = N_NODES * D / 4;
    for (int i = blockIdx.x * 256 + threadIdx.x; i < total; i += gridDim.x * 256) {
        float4 v = ((float4*)out)[i];
        int c0 = (i * 4) & (D - 1);
        float4 sc = *(const float4*)(scale + c0);
        float4 sh = *(const float4*)(shift + c0);
        v.x = v.x * sc.x + sh.x;
        v.y = v.y * sc.y + sh.y;
        v.z = v.z * sc.z + sh.z;
        v.w = v.w * sc.w + sh.w;
        ((float4*)out)[i] = v;
    }
}

extern "C" void kernel_launch(void* const* d_in, const int* in_sizes, int n_in,
                              void* d_out, int out_size, void* d_ws, size_t ws_size,
                              hipStream_t stream) {
    const float* x     = (const float*)d_in[0];
    const int*   src   = (const int*)d_in[1];
    const int*   dst   = (const int*)d_in[2];
    const float* W     = (const float*)d_in[3];
    const float* bias  = (const float*)d_in[4];
    const float* gamma = (const float*)d_in[5];
    const float* beta  = (const float*)d_in[6];
    float* out = (float*)d_out;

    char* ws = (char*)d_ws;
    size_t off = 0;
    int*   count    = (int*)(ws + off);   off += (size_t)N_NODES * 4;
    float* colsum   = (float*)(ws + off); off += D * 4;
    float* colsumsq = (float*)(ws + off); off += D * 4;
    size_t zero_bytes = off;                 // ~84 KB zeroed each call
    int*   rowstart = (int*)(ws + off);   off += (size_t)(N_NODES + 1) * 4;
    int*   cursor   = (int*)(ws + off);   off += (size_t)N_NODES * 4;
    int*   esrc     = (int*)(ws + off);   off += (size_t)N_EDGES * 4;
    float* scale    = (float*)(ws + off); off += D * 4;
    float* shift    = (float*)(ws + off); off += D * 4;
    off = (off + 255) & ~(size_t)255;
    short* Wb       = (short*)(ws + off); off += (size_t)D * D * 2;
    short* Xb       = (short*)(ws + off); off += (size_t)N_NODES * D * 2;
    short* Ab       = (short*)(ws + off); off += (size_t)MPAD * D * 2;

    hipMemsetAsync(d_ws, 0, zero_bytes, stream);

    prep<<<dim3((WCH + XCH + 255) / 256), dim3(256), 0, stream>>>(W, x, dst, Wb, Xb, count);
    scan_csr<<<dim3(1), dim3(SCAN_T), 0, stream>>>(count, rowstart, cursor);
    fill_edges<<<dim3((N_EDGES + 255) / 256), dim3(256), 0, stream>>>(src, dst, cursor, esrc);
    gather_bf16<<<dim3(MPAD / 4), dim3(256), 0, stream>>>(Xb, rowstart, esrc, Ab);
    gemm_relu_stats<<<dim3(MPAD / BM, D / BNT), dim3(256), 0, stream>>>(Ab, Wb, bias, out, colsum, colsumsq);
    bn_prep<<<dim3(1), dim3(512), 0, stream>>>(colsum, colsumsq, gamma, beta, scale, shift);
    bn_apply<<<dim3(2560), dim3(256), 0, stream>>>(out, scale, shift);
}

// Round 4
// 144.980 us; speedup vs baseline: 14.5687x; 1.0096x over previous
//
#include <hip/hip_runtime.h>
#include <hip/hip_bf16.h>

#define N_NODES 20000
#define N_EDGES 150000
#define D 512
#define MPAD 20096   // 157 * 128
#define BN_EPS 1e-5f

typedef __attribute__((ext_vector_type(8))) short s16x8;
typedef __attribute__((ext_vector_type(4))) float f32x4;

__device__ __forceinline__ short f2bf(float f) {
    union { float f; unsigned u; } v; v.f = f;
    unsigned r = (v.u + 0x7fff + ((v.u >> 16) & 1)) >> 16;
    return (short)r;
}
__device__ __forceinline__ float bf2f(short b) {
    union { unsigned u; float f; } c;
    c.u = ((unsigned)(unsigned short)b) << 16;
    return c.f;
}
__device__ __forceinline__ s16x8 cvt8(const float* p) {
    float4 a = *(const float4*)p;
    float4 b = *(const float4*)(p + 4);
    s16x8 o;
    o[0] = f2bf(a.x); o[1] = f2bf(a.y); o[2] = f2bf(a.z); o[3] = f2bf(a.w);
    o[4] = f2bf(b.x); o[5] = f2bf(b.y); o[6] = f2bf(b.z); o[7] = f2bf(b.w);
    return o;
}

__device__ __forceinline__ void load_lds16(const short* g, short* l) {
    __builtin_amdgcn_global_load_lds((const __attribute__((address_space(1))) void*)g,
                                     (__attribute__((address_space(3))) void*)l, 16, 0, 0);
}

// ---------------- zero the edge-count array (replaces pathological rocclr fill) ----------------
__global__ __launch_bounds__(256) void zero_count(int* __restrict__ count) {
    int i = blockIdx.x * 256 + threadIdx.x;          // 20 blocks: 5120 int4 slots, 5000 used
    if (i * 4 < N_NODES) {
        int4 z = make_int4(0, 0, 0, 0);
        *(int4*)(count + i * 4) = z;
    }
}

// ---------------- prep: W->bf16, x->bf16, count in-degrees ----------------
#define WCH (D * D / 8)            // 32768 chunks
#define XCH (N_NODES * D / 8)      // 1,280,000 chunks
__global__ __launch_bounds__(256) void prep(const float* __restrict__ W,
                                            const float* __restrict__ x,
                                            const int* __restrict__ dst,
                                            short* __restrict__ Wb,
                                            short* __restrict__ Xb,
                                            int* __restrict__ count) {
    int t = blockIdx.x * 256 + threadIdx.x;
    if (t < WCH) {
        *(s16x8*)(Wb + (size_t)t * 8) = cvt8(W + (size_t)t * 8);
    } else if (t < WCH + XCH) {
        size_t idx = (size_t)(t - WCH) * 8;
        *(s16x8*)(Xb + idx) = cvt8(x + idx);
    }
    if (t < N_EDGES / 8) {
        #pragma unroll
        for (int j = 0; j < 8; ++j) atomicAdd(&count[dst[t * 8 + j]], 1);
    }
}

// ---------------- CSR scan (+ zero BN stat accumulators) ----------------
#define SCAN_T 1024
__global__ __launch_bounds__(SCAN_T) void scan_csr(const int* __restrict__ count,
                                                   int* __restrict__ rowstart,
                                                   int* __restrict__ cursor,
                                                   float* __restrict__ colsum,
                                                   float* __restrict__ colsumsq) {
    int t = threadIdx.x;
    // zero the 512+512 stat accumulators (used by gemm later in the stream)
    if (t < D) colsum[t] = 0.f;
    else colsumsq[t - D] = 0.f;

    __shared__ int partial[SCAN_T];
    const int CH = (N_NODES + SCAN_T - 1) / SCAN_T;  // 20
    int base = t * CH;
    int s = 0;
    for (int j = 0; j < CH; ++j) {
        int idx = base + j;
        if (idx < N_NODES) s += count[idx];
    }
    partial[t] = s;
    __syncthreads();
    for (int off = 1; off < SCAN_T; off <<= 1) {
        int v = (t >= off) ? partial[t - off] : 0;
        __syncthreads();
        partial[t] += v;
        __syncthreads();
    }
    int run = (t == 0) ? 0 : partial[t - 1];
    for (int j = 0; j < CH; ++j) {
        int idx = base + j;
        if (idx < N_NODES) {
            rowstart[idx] = run;
            cursor[idx] = run;
            run += count[idx];
        }
    }
    if (t == SCAN_T - 1) rowstart[N_NODES] = partial[SCAN_T - 1];
}

__global__ __launch_bounds__(256) void fill_edges(const int* __restrict__ src,
                                                  const int* __restrict__ dst,
                                                  int* __restrict__ cursor,
                                                  int* __restrict__ esrc) {
    int i = blockIdx.x * 256 + threadIdx.x;
    if (i < N_EDGES) {
        int p = atomicAdd(&cursor[dst[i]], 1);
        esrc[p] = src[i];
    }
}

// ---------------- gather (bf16 in, f32 accum, bf16 out) ----------------
__global__ __launch_bounds__(256) void gather_bf16(const short* __restrict__ Xb,
                                                   const int* __restrict__ rowstart,
                                                   const int* __restrict__ esrc,
                                                   short* __restrict__ Ab) {
    int node = (blockIdx.x * 256 + threadIdx.x) >> 6;
    int lane = threadIdx.x & 63;
    if (node >= MPAD) return;
    size_t cb = (size_t)lane * 8;
    s16x8 o;
    if (node >= N_NODES) {
        o = (s16x8)0;
    } else {
        int e0 = rowstart[node], e1 = rowstart[node + 1];
        if (e0 == e1) {
            o = *(const s16x8*)(Xb + (size_t)node * D + cb);
        } else {
            float a[8] = {};
            for (int e = e0; e < e1; ++e) {
                int s = esrc[e];
                s16x8 v = *(const s16x8*)(Xb + (size_t)s * D + cb);
                #pragma unroll
                for (int i = 0; i < 8; ++i) a[i] += bf2f(v[i]);
            }
            #pragma unroll
            for (int i = 0; i < 8; ++i) o[i] = f2bf(a[i]);
        }
    }
    *(s16x8*)(Ab + (size_t)node * D + cb) = o;
}

// ---------------- GEMM: out = relu(A @ W^T + bias), fused column stats ----------------
#define BM 128
#define BNT 128
#define BK 32

__global__ __launch_bounds__(256) void gemm_relu_stats(const short* __restrict__ A,
                                                       const short* __restrict__ B,
                                                       const float* __restrict__ bias,
                                                       float* __restrict__ out,
                                                       float* __restrict__ colsum,
                                                       float* __restrict__ colsumsq) {
    __shared__ short As[BM * BK];   // 8 KB, linear [row][k]
    __shared__ short Bs[BNT * BK];  // 8 KB
    int tid = threadIdx.x;
    int lane = tid & 63;
    int wave = tid >> 6;
    int wr = wave >> 1, wc = wave & 1;
    int m0 = blockIdx.x * BM;
    int n0 = blockIdx.y * BNT;

    f32x4 acc[4][4] = {};

    int srow = lane >> 2;            // 0..15
    int scol = (lane & 3) * 8;       // shorts
    const short* Ag = A + (size_t)(m0 + wave * 32 + srow) * D + scol;
    const short* Bg = B + (size_t)(n0 + wave * 32 + srow) * D + scol;
    short* Asl = As + wave * 1024;
    short* Bsl = Bs + wave * 1024;

    for (int kt = 0; kt < D; kt += BK) {
        #pragma unroll
        for (int j = 0; j < 2; ++j) {
            load_lds16(Ag + (size_t)j * 16 * D + kt, Asl + j * 512);
            load_lds16(Bg + (size_t)j * 16 * D + kt, Bsl + j * 512);
        }
        __syncthreads();
        s16x8 af[4], bfr[4];
        int ko = (lane >> 4) * 8;
        #pragma unroll
        for (int m = 0; m < 4; ++m)
            af[m] = *(const s16x8*)(As + (wr * 64 + m * 16 + (lane & 15)) * BK + ko);
        #pragma unroll
        for (int n = 0; n < 4; ++n)
            bfr[n] = *(const s16x8*)(Bs + (wc * 64 + n * 16 + (lane & 15)) * BK + ko);
        #pragma unroll
        for (int m = 0; m < 4; ++m)
            #pragma unroll
            for (int n = 0; n < 4; ++n)
                acc[m][n] = __builtin_amdgcn_mfma_f32_16x16x32_bf16(af[m], bfr[n], acc[m][n], 0, 0, 0);
        __syncthreads();
    }

    #pragma unroll
    for (int n = 0; n < 4; ++n) {
        int col = n0 + wc * 64 + n * 16 + (lane & 15);
        float bv = bias[col];
        float s = 0.f, q = 0.f;
        #pragma unroll
        for (int m = 0; m < 4; ++m) {
            int rbase = m0 + wr * 64 + m * 16 + (lane >> 4) * 4;
            #pragma unroll
            for (int r = 0; r < 4; ++r) {
                int row = rbase + r;
                if (row < N_NODES) {
                    float v = acc[m][n][r] + bv;
                    v = v > 0.f ? v : 0.f;
                    out[(size_t)row * D + col] = v;
                    s += v;
                    q += v * v;
                }
            }
        }
        s += __shfl_xor(s, 16, 64);
        s += __shfl_xor(s, 32, 64);
        q += __shfl_xor(q, 16, 64);
        q += __shfl_xor(q, 32, 64);
        if (lane < 16) {
            atomicAdd(&colsum[col], s);
            atomicAdd(&colsumsq[col], q);
        }
    }
}

// ---------------- BN: compute scale/shift in LDS, apply in-place ----------------
__global__ __launch_bounds__(256) void bn_apply(float* __restrict__ out,
                                                const float* __restrict__ colsum,
                                                const float* __restrict__ colsumsq,
                                                const float* __restrict__ gamma,
                                                const float* __restrict__ beta) {
    __shared__ float s_scale[D], s_shift[D];
    for (int c = threadIdx.x; c < D; c += 256) {
        float mean = colsum[c] * (1.f / N_NODES);
        float var = colsumsq[c] * (1.f / N_NODES) - mean * mean;
        float rs = rsqrtf(var + BN_EPS);
        float sc = gamma[c] * rs;
        s_scale[c] = sc;
        s_shift[c] = beta[c] - mean * sc;
    }
    __syncthreads();
    const int total = N_NODES * D / 4;
    for (int i = blockIdx.x * 256 + threadIdx.x; i < total; i += gridDim.x * 256) {
        float4 v = ((float4*)out)[i];
        int c0 = (i * 4) & (D - 1);
        v.x = v.x * s_scale[c0]     + s_shift[c0];
        v.y = v.y * s_scale[c0 + 1] + s_shift[c0 + 1];
        v.z = v.z * s_scale[c0 + 2] + s_shift[c0 + 2];
        v.w = v.w * s_scale[c0 + 3] + s_shift[c0 + 3];
        ((float4*)out)[i] = v;
    }
}

extern "C" void kernel_launch(void* const* d_in, const int* in_sizes, int n_in,
                              void* d_out, int out_size, void* d_ws, size_t ws_size,
                              hipStream_t stream) {
    const float* x     = (const float*)d_in[0];
    const int*   src   = (const int*)d_in[1];
    const int*   dst   = (const int*)d_in[2];
    const float* W     = (const float*)d_in[3];
    const float* bias  = (const float*)d_in[4];
    const float* gamma = (const float*)d_in[5];
    const float* beta  = (const float*)d_in[6];
    float* out = (float*)d_out;

    char* ws = (char*)d_ws;
    size_t off = 0;
    int*   count    = (int*)(ws + off);   off += (size_t)((N_NODES + 3) & ~3) * 4;
    float* colsum   = (float*)(ws + off); off += D * 4;
    float* colsumsq = (float*)(ws + off); off += D * 4;
    int*   rowstart = (int*)(ws + off);   off += (size_t)(N_NODES + 1) * 4;
    int*   cursor   = (int*)(ws + off);   off += (size_t)N_NODES * 4;
    int*   esrc     = (int*)(ws + off);   off += (size_t)N_EDGES * 4;
    off = (off + 255) & ~(size_t)255;
    short* Wb       = (short*)(ws + off); off += (size_t)D * D * 2;
    short* Xb       = (short*)(ws + off); off += (size_t)N_NODES * D * 2;
    short* Ab       = (short*)(ws + off); off += (size_t)MPAD * D * 2;

    zero_count<<<dim3(20), dim3(256), 0, stream>>>(count);
    prep<<<dim3((WCH + XCH + 255) / 256), dim3(256), 0, stream>>>(W, x, dst, Wb, Xb, count);
    scan_csr<<<dim3(1), dim3(SCAN_T), 0, stream>>>(count, rowstart, cursor, colsum, colsumsq);
    fill_edges<<<dim3((N_EDGES + 255) / 256), dim3(256), 0, stream>>>(src, dst, cursor, esrc);
    gather_bf16<<<dim3(MPAD / 4), dim3(256), 0, stream>>>(Xb, rowstart, esrc, Ab);
    gemm_relu_stats<<<dim3(MPAD / BM, D / BNT), dim3(256), 0, stream>>>(Ab, Wb, bias, out, colsum, colsumsq);
    bn_apply<<<dim3(2048), dim3(256), 0, stream>>>(out, colsum, colsumsq, gamma, beta);
}

// Round 5
// 144.055 us; speedup vs baseline: 14.6623x; 1.0064x over previous
//
#include <hip/hip_runtime.h>
#include <hip/hip_bf16.h>

#define N_NODES 20000
#define N_EDGES 150000
#define D 512
#define MPAD 20096   // 157 * 128
#define BN_EPS 1e-5f

typedef __attribute__((ext_vector_type(8))) short s16x8;
typedef __attribute__((ext_vector_type(4))) float f32x4;

__device__ __forceinline__ short f2bf(float f) {
    union { float f; unsigned u; } v; v.f = f;
    unsigned r = (v.u + 0x7fff + ((v.u >> 16) & 1)) >> 16;
    return (short)r;
}
__device__ __forceinline__ float bf2f(short b) {
    union { unsigned u; float f; } c;
    c.u = ((unsigned)(unsigned short)b) << 16;
    return c.f;
}
__device__ __forceinline__ s16x8 cvt8(const float* p) {
    float4 a = *(const float4*)p;
    float4 b = *(const float4*)(p + 4);
    s16x8 o;
    o[0] = f2bf(a.x); o[1] = f2bf(a.y); o[2] = f2bf(a.z); o[3] = f2bf(a.w);
    o[4] = f2bf(b.x); o[5] = f2bf(b.y); o[6] = f2bf(b.z); o[7] = f2bf(b.w);
    return o;
}

__device__ __forceinline__ void load_lds16(const short* g, short* l) {
    __builtin_amdgcn_global_load_lds((const __attribute__((address_space(1))) void*)g,
                                     (__attribute__((address_space(3))) void*)l, 16, 0, 0);
}

// ---------------- zero the edge-count array ----------------
__global__ __launch_bounds__(256) void zero_count(int* __restrict__ count) {
    int i = blockIdx.x * 256 + threadIdx.x;
    if (i * 4 < N_NODES) {
        int4 z = make_int4(0, 0, 0, 0);
        *(int4*)(count + i * 4) = z;
    }
}

// ---------------- prep: W->bf16, x->bf16, count in-degrees ----------------
#define WCH (D * D / 8)            // 32768 chunks
#define XCH (N_NODES * D / 8)      // 1,280,000 chunks
__global__ __launch_bounds__(256) void prep(const float* __restrict__ W,
                                            const float* __restrict__ x,
                                            const int* __restrict__ dst,
                                            short* __restrict__ Wb,
                                            short* __restrict__ Xb,
                                            int* __restrict__ count) {
    int t = blockIdx.x * 256 + threadIdx.x;
    if (t < WCH) {
        *(s16x8*)(Wb + (size_t)t * 8) = cvt8(W + (size_t)t * 8);
    } else if (t < WCH + XCH) {
        size_t idx = (size_t)(t - WCH) * 8;
        *(s16x8*)(Xb + idx) = cvt8(x + idx);
    }
    if (t < N_EDGES / 8) {
        #pragma unroll
        for (int j = 0; j < 8; ++j) atomicAdd(&count[dst[t * 8 + j]], 1);
    }
}

// ---------------- CSR scan (+ zero BN stat accumulators) ----------------
#define SCAN_T 1024
__global__ __launch_bounds__(SCAN_T) void scan_csr(const int* __restrict__ count,
                                                   int* __restrict__ rowstart,
                                                   int* __restrict__ cursor,
                                                   float* __restrict__ colsum,
                                                   float* __restrict__ colsumsq) {
    int t = threadIdx.x;
    if (t < D) colsum[t] = 0.f;
    else colsumsq[t - D] = 0.f;

    __shared__ int partial[SCAN_T];
    const int CH = (N_NODES + SCAN_T - 1) / SCAN_T;  // 20
    int base = t * CH;
    int s = 0;
    for (int j = 0; j < CH; ++j) {
        int idx = base + j;
        if (idx < N_NODES) s += count[idx];
    }
    partial[t] = s;
    __syncthreads();
    for (int off = 1; off < SCAN_T; off <<= 1) {
        int v = (t >= off) ? partial[t - off] : 0;
        __syncthreads();
        partial[t] += v;
        __syncthreads();
    }
    int run = (t == 0) ? 0 : partial[t - 1];
    for (int j = 0; j < CH; ++j) {
        int idx = base + j;
        if (idx < N_NODES) {
            rowstart[idx] = run;
            cursor[idx] = run;
            run += count[idx];
        }
    }
    if (t == SCAN_T - 1) rowstart[N_NODES] = partial[SCAN_T - 1];
}

__global__ __launch_bounds__(256) void fill_edges(const int* __restrict__ src,
                                                  const int* __restrict__ dst,
                                                  int* __restrict__ cursor,
                                                  int* __restrict__ esrc) {
    int i = blockIdx.x * 256 + threadIdx.x;
    if (i < N_EDGES) {
        int p = atomicAdd(&cursor[dst[i]], 1);
        esrc[p] = src[i];
    }
}

// ---------------- gather (bf16 in, f32 accum, bf16 out) ----------------
__global__ __launch_bounds__(256) void gather_bf16(const short* __restrict__ Xb,
                                                   const int* __restrict__ rowstart,
                                                   const int* __restrict__ esrc,
                                                   short* __restrict__ Ab) {
    int node = (blockIdx.x * 256 + threadIdx.x) >> 6;
    int lane = threadIdx.x & 63;
    if (node >= MPAD) return;
    size_t cb = (size_t)lane * 8;
    s16x8 o;
    if (node >= N_NODES) {
        o = (s16x8)0;
    } else {
        int e0 = rowstart[node], e1 = rowstart[node + 1];
        if (e0 == e1) {
            o = *(const s16x8*)(Xb + (size_t)node * D + cb);
        } else {
            float a[8] = {};
            for (int e = e0; e < e1; ++e) {
                int s = esrc[e];
                s16x8 v = *(const s16x8*)(Xb + (size_t)s * D + cb);
                #pragma unroll
                for (int i = 0; i < 8; ++i) a[i] += bf2f(v[i]);
            }
            #pragma unroll
            for (int i = 0; i < 8; ++i) o[i] = f2bf(a[i]);
        }
    }
    *(s16x8*)(Ab + (size_t)node * D + cb) = o;
}

// ---------------- GEMM: h = relu(A @ W^T + bias) as bf16, fused column stats ----------------
// 128x256 tile, 8 waves (2M x 4N), each wave 64x64 output
#define BM 128
#define BNT 256
#define BK 32

__global__ __launch_bounds__(512) void gemm_relu_stats(const short* __restrict__ A,
                                                       const short* __restrict__ B,
                                                       const float* __restrict__ bias,
                                                       short* __restrict__ h,
                                                       float* __restrict__ colsum,
                                                       float* __restrict__ colsumsq) {
    __shared__ short As[BM * BK];   // 8 KB, linear [row][k]
    __shared__ short Bs[BNT * BK];  // 16 KB
    int tid = threadIdx.x;
    int lane = tid & 63;
    int wave = tid >> 6;             // 0..7
    int wr = wave >> 2, wc = wave & 3;
    int m0 = blockIdx.x * BM;
    int n0 = blockIdx.y * BNT;

    f32x4 acc[4][4] = {};

    // staging: A: wave w covers rows w*16..w*16+15 (one 16B issue/lane)
    //          B: wave w covers rows w*32..w*32+31 (two issues/lane)
    int srow = lane >> 2;            // 0..15
    int scol = (lane & 3) * 8;       // shorts
    const short* Ag = A + (size_t)(m0 + wave * 16 + srow) * D + scol;
    const short* Bg = B + (size_t)(n0 + wave * 32 + srow) * D + scol;
    short* Asl = As + wave * 512;    // 16 rows * 32 shorts
    short* Bsl = Bs + wave * 1024;

    for (int kt = 0; kt < D; kt += BK) {
        load_lds16(Ag + kt, Asl);
        load_lds16(Bg + kt, Bsl);
        load_lds16(Bg + (size_t)16 * D + kt, Bsl + 512);
        __syncthreads();
        s16x8 af[4], bfr[4];
        int ko = (lane >> 4) * 8;
        #pragma unroll
        for (int m = 0; m < 4; ++m)
            af[m] = *(const s16x8*)(As + (wr * 64 + m * 16 + (lane & 15)) * BK + ko);
        #pragma unroll
        for (int n = 0; n < 4; ++n)
            bfr[n] = *(const s16x8*)(Bs + (wc * 64 + n * 16 + (lane & 15)) * BK + ko);
        #pragma unroll
        for (int m = 0; m < 4; ++m)
            #pragma unroll
            for (int n = 0; n < 4; ++n)
                acc[m][n] = __builtin_amdgcn_mfma_f32_16x16x32_bf16(af[m], bfr[n], acc[m][n], 0, 0, 0);
        __syncthreads();
    }

    #pragma unroll
    for (int n = 0; n < 4; ++n) {
        int col = n0 + wc * 64 + n * 16 + (lane & 15);
        float bv = bias[col];
        float s = 0.f, q = 0.f;
        #pragma unroll
        for (int m = 0; m < 4; ++m) {
            int rbase = m0 + wr * 64 + m * 16 + (lane >> 4) * 4;
            #pragma unroll
            for (int r = 0; r < 4; ++r) {
                int row = rbase + r;
                if (row < N_NODES) {
                    float v = acc[m][n][r] + bv;
                    v = v > 0.f ? v : 0.f;
                    h[(size_t)row * D + col] = f2bf(v);
                    s += v;
                    q += v * v;
                }
            }
        }
        s += __shfl_xor(s, 16, 64);
        s += __shfl_xor(s, 32, 64);
        q += __shfl_xor(q, 16, 64);
        q += __shfl_xor(q, 32, 64);
        if (lane < 16) {
            atomicAdd(&colsum[col], s);
            atomicAdd(&colsumsq[col], q);
        }
    }
}

// ---------------- BN: compute scale/shift in LDS, read bf16 h, write f32 out ----------------
__global__ __launch_bounds__(256) void bn_apply(const short* __restrict__ h,
                                                float* __restrict__ out,
                                                const float* __restrict__ colsum,
                                                const float* __restrict__ colsumsq,
                                                const float* __restrict__ gamma,
                                                const float* __restrict__ beta) {
    __shared__ float s_scale[D], s_shift[D];
    for (int c = threadIdx.x; c < D; c += 256) {
        float mean = colsum[c] * (1.f / N_NODES);
        float var = colsumsq[c] * (1.f / N_NODES) - mean * mean;
        float rs = rsqrtf(var + BN_EPS);
        float sc = gamma[c] * rs;
        s_scale[c] = sc;
        s_shift[c] = beta[c] - mean * sc;
    }
    __syncthreads();
    const int total = N_NODES * D / 8;
    for (int i = blockIdx.x * 256 + threadIdx.x; i < total; i += gridDim.x * 256) {
        s16x8 hv = ((const s16x8*)h)[i];
        int c0 = (i * 8) & (D - 1);
        float4 o0, o1;
        o0.x = bf2f(hv[0]) * s_scale[c0]     + s_shift[c0];
        o0.y = bf2f(hv[1]) * s_scale[c0 + 1] + s_shift[c0 + 1];
        o0.z = bf2f(hv[2]) * s_scale[c0 + 2] + s_shift[c0 + 2];
        o0.w = bf2f(hv[3]) * s_scale[c0 + 3] + s_shift[c0 + 3];
        o1.x = bf2f(hv[4]) * s_scale[c0 + 4] + s_shift[c0 + 4];
        o1.y = bf2f(hv[5]) * s_scale[c0 + 5] + s_shift[c0 + 5];
        o1.z = bf2f(hv[6]) * s_scale[c0 + 6] + s_shift[c0 + 6];
        o1.w = bf2f(hv[7]) * s_scale[c0 + 7] + s_shift[c0 + 7];
        ((float4*)out)[i * 2]     = o0;
        ((float4*)out)[i * 2 + 1] = o1;
    }
}

extern "C" void kernel_launch(void* const* d_in, const int* in_sizes, int n_in,
                              void* d_out, int out_size, void* d_ws, size_t ws_size,
                              hipStream_t stream) {
    const float* x     = (const float*)d_in[0];
    const int*   src   = (const int*)d_in[1];
    const int*   dst   = (const int*)d_in[2];
    const float* W     = (const float*)d_in[3];
    const float* bias  = (const float*)d_in[4];
    const float* gamma = (const float*)d_in[5];
    const float* beta  = (const float*)d_in[6];
    float* out = (float*)d_out;

    char* ws = (char*)d_ws;
    size_t off = 0;
    int*   count    = (int*)(ws + off);   off += (size_t)((N_NODES + 3) & ~3) * 4;
    float* colsum   = (float*)(ws + off); off += D * 4;
    float* colsumsq = (float*)(ws + off); off += D * 4;
    int*   rowstart = (int*)(ws + off);   off += (size_t)(N_NODES + 1) * 4;
    int*   cursor   = (int*)(ws + off);   off += (size_t)N_NODES * 4;
    int*   esrc     = (int*)(ws + off);   off += (size_t)N_EDGES * 4;
    off = (off + 255) & ~(size_t)255;
    short* Wb       = (short*)(ws + off); off += (size_t)D * D * 2;
    short* Xb       = (short*)(ws + off); off += (size_t)N_NODES * D * 2;
    short* Ab       = (short*)(ws + off); off += (size_t)MPAD * D * 2;
    short* hbuf     = (short*)(ws + off); off += (size_t)N_NODES * D * 2;

    zero_count<<<dim3(20), dim3(256), 0, stream>>>(count);
    prep<<<dim3((WCH + XCH + 255) / 256), dim3(256), 0, stream>>>(W, x, dst, Wb, Xb, count);
    scan_csr<<<dim3(1), dim3(SCAN_T), 0, stream>>>(count, rowstart, cursor, colsum, colsumsq);
    fill_edges<<<dim3((N_EDGES + 255) / 256), dim3(256), 0, stream>>>(src, dst, cursor, esrc);
    gather_bf16<<<dim3(MPAD / 4), dim3(256), 0, stream>>>(Xb, rowstart, esrc, Ab);
    gemm_relu_stats<<<dim3(MPAD / BM, D / BNT), dim3(512), 0, stream>>>(Ab, Wb, bias, hbuf, colsum, colsumsq);
    bn_apply<<<dim3(2048), dim3(256), 0, stream>>>(hbuf, out, colsum, colsumsq, gamma, beta);
}